// Round 1
// baseline (1573.825 us; speedup 1.0000x reference)
//
#include <hip/hip_runtime.h>
#include <math.h>

#define NB 4096
#define NH 3
#define NK 32768
#define ND 128
#define RT 64          // rows per block tile
#define CT 64          // cols per subtile
#define NCH 16         // K-chunks (grid.y)
#define KCH (NK / NCH) // 2048 cols per chunk

// ---------------------------------------------------------------------------
// init: resid = inputs, quantized = 0, loss = 0, rr[row] = sum(resid^2)
__global__ __launch_bounds__(64) void init_kernel(const float* __restrict__ inp,
                                                  float* __restrict__ resid,
                                                  float* __restrict__ rr,
                                                  float* __restrict__ out) {
  int row = blockIdx.x;
  int lane = threadIdx.x;
  const float2* ip = (const float2*)(inp + row * ND);
  float2 v = ip[lane];
  ((float2*)(resid + row * ND))[lane] = v;
  ((float2*)(out + NB + row * ND))[lane] = make_float2(0.f, 0.f);
  if (lane == 0) out[row] = 0.f; // loss
  float s = v.x * v.x + v.y * v.y;
  #pragma unroll
  for (int m = 32; m; m >>= 1) s += __shfl_xor(s, m, 64);
  if (lane == 0) rr[row] = s;
}

// ---------------------------------------------------------------------------
// norms[row] = sum(W[row]^2) for all H*K rows (one wave per row)
__global__ __launch_bounds__(256) void norms_kernel(const float* __restrict__ emb,
                                                    float* __restrict__ norms) {
  int row = blockIdx.x * 4 + (threadIdx.x >> 6);
  int lane = threadIdx.x & 63;
  const float2* wp = (const float2*)(emb + (size_t)row * ND);
  float2 v = wp[lane];
  float s = v.x * v.x + v.y * v.y;
  #pragma unroll
  for (int m = 32; m; m >>= 1) s += __shfl_xor(s, m, 64);
  if (lane == 0) norms[row] = s;
}

// ---------------------------------------------------------------------------
// Fused score + per-chunk argmax. score = 2*dot(resid,W_k) - (rr + |W_k|^2)
// (== -dist, same rounding structure as the reference; argmax w/ first-index
// tie-break). Writes (best,idx) per (row, chunk).
__global__ __launch_bounds__(256) void score_kernel(const float* __restrict__ embh,
                                                    const float* __restrict__ resid,
                                                    const float* __restrict__ rr,
                                                    const float* __restrict__ normh,
                                                    float* __restrict__ partial_s,
                                                    int* __restrict__ partial_i) {
  __shared__ __align__(16) float As[ND][RT]; // 32 KB, transposed: As[d][r]
  __shared__ __align__(16) float Bs[ND][CT]; // 32 KB, transposed: Bs[d][k]

  const int tid = threadIdx.x;
  const int rowBase = blockIdx.x * RT;
  const int cb = blockIdx.y;
  const int chunkBase = cb * KCH;
  const int tx = tid & 15, ty = tid >> 4;
  const int tx4 = tx * 4, ty4 = ty * 4;

  // stage A (once per block): resid rows -> As[d][r]
  {
    const float4* rp = (const float4*)resid;
    #pragma unroll
    for (int it = 0; it < 8; ++it) {
      int idx = tid + it * 256;
      int r = idx & 63;       // consecutive lanes -> consecutive r -> 2-way LDS (free)
      int d4 = idx >> 6;
      float4 v = rp[(rowBase + r) * (ND / 4) + d4];
      As[d4 * 4 + 0][r] = v.x; As[d4 * 4 + 1][r] = v.y;
      As[d4 * 4 + 2][r] = v.z; As[d4 * 4 + 3][r] = v.w;
    }
  }

  float rrv[4];
  #pragma unroll
  for (int i = 0; i < 4; ++i) rrv[i] = rr[rowBase + ty4 + i];

  float best_s[4];
  int best_i[4];
  #pragma unroll
  for (int i = 0; i < 4; ++i) { best_s[i] = -INFINITY; best_i[i] = 0x7fffffff; }

  for (int ci = 0; ci < KCH / CT; ++ci) {
    const int kb = chunkBase + ci * CT;
    if (ci) __syncthreads(); // previous compute done before Bs overwrite
    {
      const float4* wp = (const float4*)embh;
      #pragma unroll
      for (int it = 0; it < 8; ++it) {
        int idx = tid + it * 256;
        int kk = idx & 63;
        int d4 = idx >> 6;
        float4 v = wp[(size_t)(kb + kk) * (ND / 4) + d4];
        Bs[d4 * 4 + 0][kk] = v.x; Bs[d4 * 4 + 1][kk] = v.y;
        Bs[d4 * 4 + 2][kk] = v.z; Bs[d4 * 4 + 3][kk] = v.w;
      }
    }
    __syncthreads(); // also covers As staging on first iteration

    float4 nwv4 = *(const float4*)&normh[kb + tx4];
    float nwv[4] = {nwv4.x, nwv4.y, nwv4.z, nwv4.w};

    float acc[4][4];
    #pragma unroll
    for (int i = 0; i < 4; ++i)
      #pragma unroll
      for (int j = 0; j < 4; ++j) acc[i][j] = 0.f;

    #pragma unroll 4
    for (int dd = 0; dd < ND; ++dd) {
      float4 a = *(const float4*)&As[dd][ty4]; // broadcast across tx: free
      float4 b = *(const float4*)&Bs[dd][tx4]; // consecutive banks: free
      float ar[4] = {a.x, a.y, a.z, a.w};
      float br[4] = {b.x, b.y, b.z, b.w};
      #pragma unroll
      for (int i = 0; i < 4; ++i)
        #pragma unroll
        for (int j = 0; j < 4; ++j) acc[i][j] += ar[i] * br[j];
    }

    #pragma unroll
    for (int i = 0; i < 4; ++i) {
      #pragma unroll
      for (int j = 0; j < 4; ++j) {
        float t1 = rrv[i] + nwv[j];          // fl(rr + |w|^2), as reference
        float v = 2.0f * acc[i][j] - t1;     // 2*acc exact; single rounding, matches ref
        int idx = kb + tx4 + j;
        if (v > best_s[i] || (v == best_s[i] && idx < best_i[i])) {
          best_s[i] = v; best_i[i] = idx;
        }
      }
    }
  }

  // block-level argmax reduction (overlay scratch onto As; padded stride 17)
  __syncthreads();
  float* red_s = (float*)As;
  int* red_i = ((int*)As) + RT * 17;
  #pragma unroll
  for (int i = 0; i < 4; ++i) {
    red_s[(ty4 + i) * 17 + tx] = best_s[i];
    red_i[(ty4 + i) * 17 + tx] = best_i[i];
  }
  __syncthreads();
  if (tid < RT) {
    float bs = -INFINITY;
    int bi = 0x7fffffff;
    for (int x = 0; x < 16; ++x) {
      float v = red_s[tid * 17 + x];
      int idx = red_i[tid * 17 + x];
      if (v > bs || (v == bs && idx < bi)) { bs = v; bi = idx; }
    }
    partial_s[(rowBase + tid) * NCH + cb] = bs;
    partial_i[(rowBase + tid) * NCH + cb] = bi;
  }
}

// ---------------------------------------------------------------------------
// Combine chunk partials -> code; resid -= W[c]; quantized += W[c]; new rr.
__global__ __launch_bounds__(64) void reduce_update_kernel(const float* __restrict__ embh,
                                                           float* __restrict__ resid,
                                                           float* __restrict__ rr,
                                                           const float* __restrict__ partial_s,
                                                           const int* __restrict__ partial_i,
                                                           float* __restrict__ out, int h) {
  int row = blockIdx.x;
  int lane = threadIdx.x;
  float bs = -INFINITY;
  int bi = 0x7fffffff;
  if (lane < NCH) {
    bs = partial_s[row * NCH + lane];
    bi = partial_i[row * NCH + lane];
  }
  #pragma unroll
  for (int m = 8; m; m >>= 1) {
    float os = __shfl_xor(bs, m, 64);
    int oi = __shfl_xor(bi, m, 64);
    if (os > bs || (os == bs && oi < bi)) { bs = os; bi = oi; }
  }
  int c = __shfl(bi, 0, 64);
  if (lane == 0) out[NB + NB * ND + row * NH + h] = (float)c; // codes as f32

  const float* w = embh + (size_t)c * ND;
  float q0 = w[lane], q1 = w[lane + 64];
  float r0 = resid[row * ND + lane] - q0;
  float r1 = resid[row * ND + lane + 64] - q1;
  resid[row * ND + lane] = r0;
  resid[row * ND + lane + 64] = r1;
  out[NB + row * ND + lane] += q0;        // quantized accumulates in ref order
  out[NB + row * ND + lane + 64] += q1;
  float s = r0 * r0 + r1 * r1;
  #pragma unroll
  for (int m = 32; m; m >>= 1) s += __shfl_xor(s, m, 64);
  if (lane == 0) rr[row] = s;
}

// ---------------------------------------------------------------------------
extern "C" void kernel_launch(void* const* d_in, const int* in_sizes, int n_in,
                              void* d_out, int out_size, void* d_ws, size_t ws_size,
                              hipStream_t stream) {
  const float* inp = (const float*)d_in[0]; // (4096,1,128)
  const float* emb = (const float*)d_in[1]; // (3,32768,128)
  float* out = (float*)d_out;               // loss(4096) | quantized(4096*128) | codes(4096*3)

  float* resid = (float*)d_ws;              // NB*ND
  float* rr = resid + NB * ND;              // NB
  float* norms = rr + NB;                   // NH*NK
  float* ps = norms + NH * NK;              // NB*NCH
  int* pi = (int*)(ps + NB * NCH);          // NB*NCH

  hipLaunchKernelGGL(init_kernel, dim3(NB), dim3(64), 0, stream, inp, resid, rr, out);
  hipLaunchKernelGGL(norms_kernel, dim3(NH * NK / 4), dim3(256), 0, stream, emb, norms);
  for (int h = 0; h < NH; ++h) {
    hipLaunchKernelGGL(score_kernel, dim3(NB / RT, NCH), dim3(256), 0, stream,
                       emb + (size_t)h * NK * ND, resid, rr, norms + h * NK, ps, pi);
    hipLaunchKernelGGL(reduce_update_kernel, dim3(NB), dim3(64), 0, stream,
                       emb + (size_t)h * NK * ND, resid, rr, ps, pi, out, h);
  }
}

// Round 2
// 735.532 us; speedup vs baseline: 2.1397x; 2.1397x over previous
//
#include <hip/hip_runtime.h>
#include <math.h>

#define NB 4096
#define NH 3
#define NK 32768
#define ND 128
#define KE 384          // extended K: [rh*wh | rh*wl | rl*wh]
#define BM 128
#define BN 128
#define BK 64
#define NCB (NK / BN)   // 256 column blocks per head

typedef _Float16 half8_t __attribute__((ext_vector_type(8)));
typedef float f32x4 __attribute__((ext_vector_type(4)));
typedef __attribute__((address_space(1))) const unsigned int gu32_t;
typedef __attribute__((address_space(3))) unsigned int lu32_t;

// ---------------------------------------------------------------------------
// init: resid = inputs, quantized = 0, loss = 0, rr[row] = sum(resid^2)
__global__ __launch_bounds__(64) void init_kernel(const float* __restrict__ inp,
                                                  float* __restrict__ resid,
                                                  float* __restrict__ rr,
                                                  float* __restrict__ out) {
  int row = blockIdx.x;
  int lane = threadIdx.x;
  const float2* ip = (const float2*)(inp + row * ND);
  float2 v = ip[lane];
  ((float2*)(resid + row * ND))[lane] = v;
  ((float2*)(out + NB + row * ND))[lane] = make_float2(0.f, 0.f);
  if (lane == 0) out[row] = 0.f; // loss
  float s = v.x * v.x + v.y * v.y;
  #pragma unroll
  for (int m = 32; m; m >>= 1) s += __shfl_xor(s, m, 64);
  if (lane == 0) rr[row] = s;
}

// ---------------------------------------------------------------------------
// norms[row] = sum(W[row]^2) for all H*K rows (one wave per row), fp32 exact
__global__ __launch_bounds__(256) void norms_kernel(const float* __restrict__ emb,
                                                    float* __restrict__ norms) {
  int row = blockIdx.x * 4 + (threadIdx.x >> 6);
  int lane = threadIdx.x & 63;
  const float2* wp = (const float2*)(emb + (size_t)row * ND);
  float2 v = wp[lane];
  float s = v.x * v.x + v.y * v.y;
  #pragma unroll
  for (int m = 32; m; m >>= 1) s += __shfl_xor(s, m, 64);
  if (lane == 0) norms[row] = s;
}

// ---------------------------------------------------------------------------
// fp32 -> (hi,lo) fp16 split, extended-K layouts.
// Bext row n: [wh(128) | wl(128) | wh(128)]
__global__ __launch_bounds__(256) void split_w_kernel(const float* __restrict__ W,
                                                      _Float16* __restrict__ Bext) {
  int idx = blockIdx.x * 256 + threadIdx.x; // over NK*ND
  int n = idx >> 7, k = idx & 127;
  float x = W[idx];
  _Float16 h = (_Float16)x;
  _Float16 l = (_Float16)(x - (float)h);
  size_t base = (size_t)n * KE;
  Bext[base + k] = h;
  Bext[base + 128 + k] = l;
  Bext[base + 256 + k] = h;
}

// Aext row r: [rh(128) | rh(128) | rl(128)]
__global__ __launch_bounds__(256) void split_a_kernel(const float* __restrict__ resid,
                                                      _Float16* __restrict__ Aext) {
  int idx = blockIdx.x * 256 + threadIdx.x; // over NB*ND
  int r = idx >> 7, k = idx & 127;
  float x = resid[idx];
  _Float16 h = (_Float16)x;
  _Float16 l = (_Float16)(x - (float)h);
  size_t base = (size_t)r * KE;
  Aext[base + k] = h;
  Aext[base + 128 + k] = h;
  Aext[base + 256 + k] = l;
}

// ---------------------------------------------------------------------------
// MFMA score kernel: 128x128 tile, K=384 f16 GEMM, fused score+argmax.
// score = 2*dot - fl(rr + |w|^2), argmax w/ first-index tie-break.
// LDS layout: row-major [row][k] with 16B k-chunks XOR-swizzled by (row&7)
// so both global_load_lds staging (linear lane order) and ds_read_b128
// fragment reads are conflict-free without padding.
__global__ __launch_bounds__(256) void score_mfma_kernel(
    const _Float16* __restrict__ Aext, const _Float16* __restrict__ Bext,
    const float* __restrict__ rr, const float* __restrict__ normh,
    float* __restrict__ partial_s, int* __restrict__ partial_i) {
  __shared__ __align__(16) _Float16 Ash[BM * BK]; // 16 KB
  __shared__ __align__(16) _Float16 Bsh[BN * BK]; // 16 KB

  const int tid = threadIdx.x;
  const int lane = tid & 63;
  const int w = tid >> 6;            // wave 0..3
  const int wm = w >> 1, wn = w & 1; // 2x2 wave grid, 64x64 each
  const int rowBase = blockIdx.x * BM;
  const int colBase = blockIdx.y * BN;

  const int mloc = lane >> 3;                 // row within 8-row stage group
  const int chunk = (lane & 7) ^ (mloc & 7);  // which k-chunk this lane fetches

  f32x4 acc[4][4];
  #pragma unroll
  for (int i = 0; i < 4; ++i)
    #pragma unroll
    for (int j = 0; j < 4; ++j) acc[i][j] = (f32x4){0.f, 0.f, 0.f, 0.f};

  for (int it = 0; it < KE / BK; ++it) {
    const int kb = it * BK;
    if (it) __syncthreads(); // previous compute done before LDS overwrite
    // stage: each wave issues 4 A + 4 B global_load_lds (8 rows x 64 k each)
    #pragma unroll
    for (int i = 0; i < 4; ++i) {
      int rowA = w * 32 + i * 8 + mloc; // 0..127 within tile
      const _Float16* gA = Aext + (size_t)(rowBase + rowA) * KE + kb + chunk * 8;
      __builtin_amdgcn_global_load_lds((gu32_t*)gA, (lu32_t*)&Ash[(w * 32 + i * 8) * BK], 16, 0, 0);
      const _Float16* gB = Bext + (size_t)(colBase + rowA) * KE + kb + chunk * 8;
      __builtin_amdgcn_global_load_lds((gu32_t*)gB, (lu32_t*)&Bsh[(w * 32 + i * 8) * BK], 16, 0, 0);
    }
    __syncthreads(); // drains vmcnt, staging visible

    #pragma unroll
    for (int ks = 0; ks < 2; ++ks) {
      const int q = lane >> 4;
      const int ck = ks * 4 + q; // k-chunk index for this lane's fragment
      half8_t af[4], bf[4];
      #pragma unroll
      for (int mt = 0; mt < 4; ++mt) {
        int m = wm * 64 + mt * 16 + (lane & 15);
        af[mt] = *(const half8_t*)&Ash[m * BK + (ck ^ (m & 7)) * 8];
      }
      #pragma unroll
      for (int tn = 0; tn < 4; ++tn) {
        int n = wn * 64 + tn * 16 + (lane & 15);
        bf[tn] = *(const half8_t*)&Bsh[n * BK + (ck ^ (n & 7)) * 8];
      }
      #pragma unroll
      for (int mt = 0; mt < 4; ++mt)
        #pragma unroll
        for (int tn = 0; tn < 4; ++tn)
          acc[mt][tn] = __builtin_amdgcn_mfma_f32_16x16x32_f16(af[mt], bf[tn], acc[mt][tn], 0, 0, 0);
    }
  }

  // ---- epilogue: score + argmax ----
  // C layout: col = lane&15 (within 16-tile), row = (lane>>4)*4 + reg
  const int q = lane >> 4;
  float wnv[4];
  #pragma unroll
  for (int tn = 0; tn < 4; ++tn)
    wnv[tn] = normh[colBase + wn * 64 + tn * 16 + (lane & 15)];

  float bs[16]; int bi[16];
  #pragma unroll
  for (int mt = 0; mt < 4; ++mt) {
    #pragma unroll
    for (int reg = 0; reg < 4; ++reg) {
      int grow = rowBase + wm * 64 + mt * 16 + q * 4 + reg;
      float rrv = rr[grow];
      float best = -INFINITY; int besti = 0x7fffffff;
      #pragma unroll
      for (int tn = 0; tn < 4; ++tn) {
        float t1 = rrv + wnv[tn];              // fl(rr + |w|^2), as reference
        float v = 2.0f * acc[mt][tn][reg] - t1; // exact 2x, single rounding
        int idx = colBase + wn * 64 + tn * 16 + (lane & 15);
        if (v > best || (v == best && idx < besti)) { best = v; besti = idx; }
      }
      bs[mt * 4 + reg] = best; bi[mt * 4 + reg] = besti;
    }
  }

  __syncthreads(); // all MFMA LDS reads done before overlaying scratch
  float* red_s = (float*)Ash;      // [128][2]
  int* red_i = (int*)Ash + 256;    // [128][2]
  #pragma unroll
  for (int t = 0; t < 16; ++t) {
    float s = bs[t]; int ii = bi[t];
    #pragma unroll
    for (int mask = 1; mask <= 8; mask <<= 1) {
      float os = __shfl_xor(s, mask, 64);
      int oi = __shfl_xor(ii, mask, 64);
      if (os > s || (os == s && oi < ii)) { s = os; ii = oi; }
    }
    if ((lane & 15) == 0) {
      int mt = t >> 2, reg = t & 3;
      int rloc = wm * 64 + mt * 16 + q * 4 + reg;
      red_s[rloc * 2 + wn] = s;
      red_i[rloc * 2 + wn] = ii;
    }
  }
  __syncthreads();
  if (tid < BM) {
    float s0 = red_s[tid * 2], s1 = red_s[tid * 2 + 1];
    int i0 = red_i[tid * 2], i1 = red_i[tid * 2 + 1];
    bool take1 = (s1 > s0) || (s1 == s0 && i1 < i0);
    partial_s[(size_t)(rowBase + tid) * NCB + blockIdx.y] = take1 ? s1 : s0;
    partial_i[(size_t)(rowBase + tid) * NCB + blockIdx.y] = take1 ? i1 : i0;
  }
}

// ---------------------------------------------------------------------------
// Combine col-block partials -> code; resid -= W[c]; quantized += W[c]; new rr.
__global__ __launch_bounds__(64) void reduce_update_kernel(const float* __restrict__ embh,
                                                           float* __restrict__ resid,
                                                           float* __restrict__ rr,
                                                           const float* __restrict__ ps,
                                                           const int* __restrict__ pi,
                                                           float* __restrict__ out, int h) {
  int row = blockIdx.x;
  int lane = threadIdx.x;
  float bs = -INFINITY;
  int bi = 0x7fffffff;
  #pragma unroll
  for (int j = 0; j < 4; ++j) {
    int c = lane * 4 + j;
    float s = ps[(size_t)row * NCB + c];
    int idx = pi[(size_t)row * NCB + c];
    if (s > bs || (s == bs && idx < bi)) { bs = s; bi = idx; }
  }
  #pragma unroll
  for (int m = 32; m; m >>= 1) {
    float os = __shfl_xor(bs, m, 64);
    int oi = __shfl_xor(bi, m, 64);
    if (os > bs || (os == bs && oi < bi)) { bs = os; bi = oi; }
  }
  int c = __shfl(bi, 0, 64);
  if (lane == 0) out[NB + NB * ND + row * NH + h] = (float)c; // codes as f32

  const float* wv = embh + (size_t)c * ND;
  float q0 = wv[lane], q1 = wv[lane + 64];
  float r0 = resid[row * ND + lane] - q0;
  float r1 = resid[row * ND + lane + 64] - q1;
  resid[row * ND + lane] = r0;
  resid[row * ND + lane + 64] = r1;
  out[NB + row * ND + lane] += q0;
  out[NB + row * ND + lane + 64] += q1;
  float s = r0 * r0 + r1 * r1;
  #pragma unroll
  for (int m = 32; m; m >>= 1) s += __shfl_xor(s, m, 64);
  if (lane == 0) rr[row] = s;
}

// ---------------------------------------------------------------------------
extern "C" void kernel_launch(void* const* d_in, const int* in_sizes, int n_in,
                              void* d_out, int out_size, void* d_ws, size_t ws_size,
                              hipStream_t stream) {
  const float* inp = (const float*)d_in[0]; // (4096,1,128)
  const float* emb = (const float*)d_in[1]; // (3,32768,128)
  float* out = (float*)d_out;               // loss | quantized | codes

  float* resid = (float*)d_ws;                       // NB*ND f32
  float* rr = resid + NB * ND;                       // NB
  float* norms = rr + NB;                            // NH*NK
  float* ps = norms + NH * NK;                       // NB*NCB f32
  int* pi = (int*)(ps + (size_t)NB * NCB);           // NB*NCB i32
  _Float16* Aext = (_Float16*)(pi + (size_t)NB * NCB); // NB*KE f16
  _Float16* Bext = Aext + (size_t)NB * KE;             // NK*KE f16  (~38 MB total)

  hipLaunchKernelGGL(init_kernel, dim3(NB), dim3(64), 0, stream, inp, resid, rr, out);
  hipLaunchKernelGGL(norms_kernel, dim3(NH * NK / 4), dim3(256), 0, stream, emb, norms);
  for (int h = 0; h < NH; ++h) {
    hipLaunchKernelGGL(split_a_kernel, dim3(NB * ND / 256), dim3(256), 0, stream, resid, Aext);
    hipLaunchKernelGGL(split_w_kernel, dim3(NK * ND / 256), dim3(256), 0, stream,
                       emb + (size_t)h * NK * ND, Bext);
    hipLaunchKernelGGL(score_mfma_kernel, dim3(NB / BM, NK / BN), dim3(256), 0, stream,
                       Aext, Bext, rr, norms + (size_t)h * NK, ps, pi);
    hipLaunchKernelGGL(reduce_update_kernel, dim3(NB), dim3(64), 0, stream,
                       emb + (size_t)h * NK * ND, resid, rr, ps, pi, out, h);
  }
}

// Round 3
// 684.127 us; speedup vs baseline: 2.3005x; 1.0751x over previous
//
#include <hip/hip_runtime.h>
#include <math.h>

#define NB 4096
#define NH 3
#define NK 32768
#define ND 128
#define KE 384          // extended K: [rh*wh | rh*wl | rl*wh]
#define BM 128
#define BN 256          // cols per block (2 col-tiles of 128 per wave pair)
#define BK 64
#define NCB (NK / BN)   // 128 column groups per head
#define NRB (NB / BM)   // 32 row blocks

typedef _Float16 half8_t __attribute__((ext_vector_type(8)));
typedef float f32x4 __attribute__((ext_vector_type(4)));
typedef __attribute__((address_space(1))) const unsigned int gu32_t;
typedef __attribute__((address_space(3))) unsigned int lu32_t;

// ---------------------------------------------------------------------------
// init: resid = inputs, quantized = 0, loss = 0, rr[row] = sum(resid^2)
__global__ __launch_bounds__(64) void init_kernel(const float* __restrict__ inp,
                                                  float* __restrict__ resid,
                                                  float* __restrict__ rr,
                                                  float* __restrict__ out) {
  int row = blockIdx.x;
  int lane = threadIdx.x;
  const float2* ip = (const float2*)(inp + row * ND);
  float2 v = ip[lane];
  ((float2*)(resid + row * ND))[lane] = v;
  ((float2*)(out + NB + row * ND))[lane] = make_float2(0.f, 0.f);
  if (lane == 0) out[row] = 0.f; // loss
  float s = v.x * v.x + v.y * v.y;
  #pragma unroll
  for (int m = 32; m; m >>= 1) s += __shfl_xor(s, m, 64);
  if (lane == 0) rr[row] = s;
}

// ---------------------------------------------------------------------------
// norms[row] = sum(W[row]^2) for all H*K rows (one wave per row), fp32 exact
__global__ __launch_bounds__(256) void norms_kernel(const float* __restrict__ emb,
                                                    float* __restrict__ norms) {
  int row = blockIdx.x * 4 + (threadIdx.x >> 6);
  int lane = threadIdx.x & 63;
  const float2* wp = (const float2*)(emb + (size_t)row * ND);
  float2 v = wp[lane];
  float s = v.x * v.x + v.y * v.y;
  #pragma unroll
  for (int m = 32; m; m >>= 1) s += __shfl_xor(s, m, 64);
  if (lane == 0) norms[row] = s;
}

// ---------------------------------------------------------------------------
// fp32 -> (hi,lo) fp16 split, extended-K layouts.
// Bext row n: [wh(128) | wl(128) | wh(128)]
__global__ __launch_bounds__(256) void split_w_kernel(const float* __restrict__ W,
                                                      _Float16* __restrict__ Bext) {
  int idx = blockIdx.x * 256 + threadIdx.x; // over NK*ND
  int n = idx >> 7, k = idx & 127;
  float x = W[idx];
  _Float16 h = (_Float16)x;
  _Float16 l = (_Float16)(x - (float)h);
  size_t base = (size_t)n * KE;
  Bext[base + k] = h;
  Bext[base + 128 + k] = l;
  Bext[base + 256 + k] = h;
}

// Aext row r: [rh(128) | rh(128) | rl(128)]
__global__ __launch_bounds__(256) void split_a_kernel(const float* __restrict__ resid,
                                                      _Float16* __restrict__ Aext) {
  int idx = blockIdx.x * 256 + threadIdx.x; // over NB*ND
  int r = idx >> 7, k = idx & 127;
  float x = resid[idx];
  _Float16 h = (_Float16)x;
  _Float16 l = (_Float16)(x - (float)h);
  size_t base = (size_t)r * KE;
  Aext[base + k] = h;
  Aext[base + 128 + k] = h;
  Aext[base + 256 + k] = l;
}

// ---------------------------------------------------------------------------
// MFMA score kernel: 128x256 block tile, K=384 f16 GEMM, fused score+argmax.
// score = 2*dot - fl(rr + |w|^2), argmax w/ first-index tie-break.
// LDS layout: row-major [row][kchunk] with 16B k-chunks XOR-swizzled by
// (row&7): conflict-free for both staging and ds_read_b128 fragment reads.
// Block remap: xcd = bid&7 owns col-groups [16*xcd, 16*xcd+16) so each
// XCD's L2 holds a 3.1 MB B-slice (fits 4 MB), col-group fastest.
__global__ __launch_bounds__(256, 2) void score_mfma_kernel(
    const _Float16* __restrict__ Aext, const _Float16* __restrict__ Bext,
    const float* __restrict__ rr, const float* __restrict__ normh,
    float* __restrict__ partial_s, int* __restrict__ partial_i) {
  __shared__ __align__(16) _Float16 Ash[BM * BK]; // 16 KB
  __shared__ __align__(16) _Float16 Bsh[BN * BK]; // 32 KB

  const int bid = blockIdx.x;
  const int xcd = bid & 7, idx = bid >> 3;
  const int cg = xcd * 16 + (idx & 15); // col group 0..127
  const int rowb = idx >> 4;            // row block 0..31
  const int rowBase = rowb * BM;
  const int colBase = cg * BN;

  const int tid = threadIdx.x;
  const int lane = tid & 63;
  const int w = tid >> 6;            // wave 0..3
  const int wm = w >> 1, wn = w & 1; // 2x2 wave grid; wave tile 64 x 128
  const int mloc = lane >> 3;                // row within 8-row stage group
  const int chunk = (lane & 7) ^ (mloc & 7); // k-chunk this lane fetches

  f32x4 acc[4][8];
  #pragma unroll
  for (int i = 0; i < 4; ++i)
    #pragma unroll
    for (int j = 0; j < 8; ++j) acc[i][j] = (f32x4){0.f, 0.f, 0.f, 0.f};

  for (int it = 0; it < KE / BK; ++it) {
    const int kb = it * BK;
    if (it) __syncthreads(); // previous compute done before LDS overwrite
    // stage A: 4 loads/wave (8 rows x 64k each), B: 8 loads/wave
    #pragma unroll
    for (int i = 0; i < 4; ++i) {
      int rowA = w * 32 + i * 8 + mloc; // 0..127
      const _Float16* gA = Aext + (size_t)(rowBase + rowA) * KE + kb + chunk * 8;
      __builtin_amdgcn_global_load_lds((gu32_t*)gA, (lu32_t*)&Ash[(w * 32 + i * 8) * BK], 16, 0, 0);
    }
    #pragma unroll
    for (int j = 0; j < 8; ++j) {
      int colB = w * 64 + j * 8 + mloc; // 0..255
      const _Float16* gB = Bext + (size_t)(colBase + colB) * KE + kb + chunk * 8;
      __builtin_amdgcn_global_load_lds((gu32_t*)gB, (lu32_t*)&Bsh[(w * 64 + j * 8) * BK], 16, 0, 0);
    }
    __syncthreads(); // drains vmcnt, staging visible

    #pragma unroll
    for (int ks = 0; ks < 2; ++ks) {
      const int q = lane >> 4;
      const int ck = ks * 4 + q; // k-chunk index for this lane's fragment
      half8_t af[4], bf[8];
      #pragma unroll
      for (int mt = 0; mt < 4; ++mt) {
        int m = wm * 64 + mt * 16 + (lane & 15);
        af[mt] = *(const half8_t*)&Ash[m * BK + (ck ^ (m & 7)) * 8];
      }
      #pragma unroll
      for (int tn = 0; tn < 8; ++tn) {
        int n = wn * 128 + tn * 16 + (lane & 15);
        bf[tn] = *(const half8_t*)&Bsh[n * BK + (ck ^ (n & 7)) * 8];
      }
      #pragma unroll
      for (int mt = 0; mt < 4; ++mt)
        #pragma unroll
        for (int tn = 0; tn < 8; ++tn)
          acc[mt][tn] = __builtin_amdgcn_mfma_f32_16x16x32_f16(af[mt], bf[tn], acc[mt][tn], 0, 0, 0);
    }
  }

  // ---- epilogue: score + argmax ----
  // C layout: col = lane&15 (within 16-tile), row = (lane>>4)*4 + reg
  const int q = lane >> 4;
  float wnv[8];
  #pragma unroll
  for (int tn = 0; tn < 8; ++tn)
    wnv[tn] = normh[colBase + wn * 128 + tn * 16 + (lane & 15)];

  float bs[16]; int bi[16];
  #pragma unroll
  for (int mt = 0; mt < 4; ++mt) {
    #pragma unroll
    for (int reg = 0; reg < 4; ++reg) {
      int grow = rowBase + wm * 64 + mt * 16 + q * 4 + reg;
      float rrv = rr[grow];
      float best = -INFINITY; int besti = 0x7fffffff;
      #pragma unroll
      for (int tn = 0; tn < 8; ++tn) {
        float t1 = rrv + wnv[tn];               // fl(rr + |w|^2), as reference
        float v = 2.0f * acc[mt][tn][reg] - t1; // exact 2x, single rounding
        int cidx = colBase + wn * 128 + tn * 16 + (lane & 15);
        if (v > best || (v == best && cidx < besti)) { best = v; besti = cidx; }
      }
      bs[mt * 4 + reg] = best; bi[mt * 4 + reg] = besti;
    }
  }

  __syncthreads(); // all MFMA LDS reads done before overlaying scratch
  float* red_s = (float*)Ash;      // [128][2]
  int* red_i = (int*)Ash + 256;    // [128][2]
  #pragma unroll
  for (int t = 0; t < 16; ++t) {
    float s = bs[t]; int ii = bi[t];
    #pragma unroll
    for (int mask = 1; mask <= 8; mask <<= 1) {
      float os = __shfl_xor(s, mask, 64);
      int oi = __shfl_xor(ii, mask, 64);
      if (os > s || (os == s && oi < ii)) { s = os; ii = oi; }
    }
    if ((lane & 15) == 0) {
      int mt = t >> 2, reg = t & 3;
      int rloc = wm * 64 + mt * 16 + q * 4 + reg;
      red_s[rloc * 2 + wn] = s;
      red_i[rloc * 2 + wn] = ii;
    }
  }
  __syncthreads();
  if (tid < BM) {
    float s0 = red_s[tid * 2], s1 = red_s[tid * 2 + 1];
    int i0 = red_i[tid * 2], i1 = red_i[tid * 2 + 1];
    bool take1 = (s1 > s0) || (s1 == s0 && i1 < i0);
    partial_s[(size_t)(rowBase + tid) * NCB + cg] = take1 ? s1 : s0;
    partial_i[(size_t)(rowBase + tid) * NCB + cg] = take1 ? i1 : i0;
  }
}

// ---------------------------------------------------------------------------
// Combine col-group partials -> code; resid -= W[c]; quantized += W[c]; new rr.
__global__ __launch_bounds__(64) void reduce_update_kernel(const float* __restrict__ embh,
                                                           float* __restrict__ resid,
                                                           float* __restrict__ rr,
                                                           const float* __restrict__ ps,
                                                           const int* __restrict__ pi,
                                                           float* __restrict__ out, int h) {
  int row = blockIdx.x;
  int lane = threadIdx.x;
  float bs = -INFINITY;
  int bi = 0x7fffffff;
  #pragma unroll
  for (int j = 0; j < NCB / 64; ++j) {
    int c = lane * (NCB / 64) + j;
    float s = ps[(size_t)row * NCB + c];
    int idxv = pi[(size_t)row * NCB + c];
    if (s > bs || (s == bs && idxv < bi)) { bs = s; bi = idxv; }
  }
  #pragma unroll
  for (int m = 32; m; m >>= 1) {
    float os = __shfl_xor(bs, m, 64);
    int oi = __shfl_xor(bi, m, 64);
    if (os > bs || (os == bs && oi < bi)) { bs = os; bi = oi; }
  }
  int c = __shfl(bi, 0, 64);
  if (lane == 0) out[NB + NB * ND + row * NH + h] = (float)c; // codes as f32

  const float* wv = embh + (size_t)c * ND;
  float q0 = wv[lane], q1 = wv[lane + 64];
  float r0 = resid[row * ND + lane] - q0;
  float r1 = resid[row * ND + lane + 64] - q1;
  resid[row * ND + lane] = r0;
  resid[row * ND + lane + 64] = r1;
  out[NB + row * ND + lane] += q0;
  out[NB + row * ND + lane + 64] += q1;
  float s = r0 * r0 + r1 * r1;
  #pragma unroll
  for (int m = 32; m; m >>= 1) s += __shfl_xor(s, m, 64);
  if (lane == 0) rr[row] = s;
}

// ---------------------------------------------------------------------------
extern "C" void kernel_launch(void* const* d_in, const int* in_sizes, int n_in,
                              void* d_out, int out_size, void* d_ws, size_t ws_size,
                              hipStream_t stream) {
  const float* inp = (const float*)d_in[0]; // (4096,1,128)
  const float* emb = (const float*)d_in[1]; // (3,32768,128)
  float* out = (float*)d_out;               // loss | quantized | codes

  float* resid = (float*)d_ws;                         // NB*ND f32
  float* rr = resid + NB * ND;                         // NB
  float* norms = rr + NB;                              // NH*NK
  float* ps = norms + NH * NK;                         // NB*NCB f32
  int* pi = (int*)(ps + (size_t)NB * NCB);             // NB*NCB i32
  _Float16* Aext = (_Float16*)(pi + (size_t)NB * NCB); // NB*KE f16
  _Float16* Bext = Aext + (size_t)NB * KE;             // NK*KE f16

  hipLaunchKernelGGL(init_kernel, dim3(NB), dim3(64), 0, stream, inp, resid, rr, out);
  hipLaunchKernelGGL(norms_kernel, dim3(NH * NK / 4), dim3(256), 0, stream, emb, norms);
  for (int h = 0; h < NH; ++h) {
    hipLaunchKernelGGL(split_a_kernel, dim3(NB * ND / 256), dim3(256), 0, stream, resid, Aext);
    hipLaunchKernelGGL(split_w_kernel, dim3(NK * ND / 256), dim3(256), 0, stream,
                       emb + (size_t)h * NK * ND, Bext);
    hipLaunchKernelGGL(score_mfma_kernel, dim3(NRB * NCB), dim3(256), 0, stream,
                       Aext, Bext, rr, norms + (size_t)h * NK, ps, pi);
    hipLaunchKernelGGL(reduce_update_kernel, dim3(NB), dim3(64), 0, stream,
                       emb + (size_t)h * NK * ND, resid, rr, ps, pi, out, h);
  }
}